// Round 1
// baseline (561.602 us; speedup 1.0000x reference)
//
#include <hip/hip_runtime.h>

typedef unsigned short u16;
typedef __attribute__((ext_vector_type(4))) float f32x4;
typedef __attribute__((ext_vector_type(8))) short short8;

// ---------------- constants ----------------
// B=8 QLEN=256 D=1024 H=16 HD=64 FFN=4096 PAGE=16 KV_TOTAL=4096 P=256
// PREFIX=3840 SCALE=0.125
#define MODE_QKV 0
#define MODE_WO  1
#define MODE_F1  2
#define MODE_F2  3

__device__ inline u16 f2bf(float f) {
    union { float f; unsigned int u; } x; x.f = f;
    unsigned int u = x.u;
    unsigned int r = (u + 0x7FFFu + ((u >> 16) & 1u)) >> 16;
    return (u16)r;
}

// ---------------- transpose + cast: src f32 [K][N] -> dst bf16 [N][K] ----------------
__global__ __launch_bounds__(256) void transpose_cast(const float* __restrict__ src,
                                                      u16* __restrict__ dst, int K, int N) {
    __shared__ float t[32][33];
    int n0 = blockIdx.x * 32, k0 = blockIdx.y * 32;
    int tx = threadIdx.x, ty = threadIdx.y; // (32,8)
#pragma unroll
    for (int j = 0; j < 32; j += 8)
        t[ty + j][tx] = src[(size_t)(k0 + ty + j) * N + n0 + tx];
    __syncthreads();
#pragma unroll
    for (int j = 0; j < 32; j += 8)
        dst[(size_t)(n0 + ty + j) * K + k0 + tx] = f2bf(t[tx][ty + j]);
}

// ---------------- cast f32 -> bf16 (8 per thread) ----------------
__global__ __launch_bounds__(256) void cast_f2b(const float* __restrict__ s,
                                                u16* __restrict__ d, int n8) {
    int i = blockIdx.x * 256 + threadIdx.x;
    if (i >= n8) return;
    const float4* p = (const float4*)(s + (size_t)i * 8);
    float4 a = p[0], b = p[1];
    u16 t[8] = {f2bf(a.x), f2bf(a.y), f2bf(a.z), f2bf(a.w),
                f2bf(b.x), f2bf(b.y), f2bf(b.z), f2bf(b.w)};
    *(uint4*)(d + (size_t)i * 8) = *(const uint4*)t;
}

// ---------------- float4 grid-stride copy ----------------
__global__ __launch_bounds__(256) void copy_f4(const float4* __restrict__ s,
                                               float4* __restrict__ d, int n4) {
    int i = blockIdx.x * 256 + threadIdx.x;
    int stride = gridDim.x * 256;
    for (; i < n4; i += stride) d[i] = s[i];
}

// ---------------- layer norm over rows of 1024 ----------------
__global__ __launch_bounds__(256) void ln_row(const float* __restrict__ in,
                                              const float* __restrict__ g,
                                              const float* __restrict__ be,
                                              float* __restrict__ outf,
                                              u16* __restrict__ outb) {
    int row = blockIdx.x;
    int tid = threadIdx.x;
    const float* p = in + (size_t)row * 1024 + tid * 4;
    float4 v = *(const float4*)p;
    float s = v.x + v.y + v.z + v.w;
#pragma unroll
    for (int m = 1; m < 64; m <<= 1) s += __shfl_xor(s, m, 64);
    __shared__ float red1[4], red2[4];
    int w = tid >> 6;
    if ((tid & 63) == 0) red1[w] = s;
    __syncthreads();
    float mu = (red1[0] + red1[1] + red1[2] + red1[3]) * (1.0f / 1024.0f);
    float dx = v.x - mu, dy = v.y - mu, dz = v.z - mu, dw = v.w - mu;
    float q = dx * dx + dy * dy + dz * dz + dw * dw;
#pragma unroll
    for (int m = 1; m < 64; m <<= 1) q += __shfl_xor(q, m, 64);
    if ((tid & 63) == 0) red2[w] = q;
    __syncthreads();
    float var = (red2[0] + red2[1] + red2[2] + red2[3]) * (1.0f / 1024.0f);
    float rs = rsqrtf(var + 1e-5f);
    int c = tid * 4;
    float o0 = dx * rs * g[c + 0] + be[c + 0];
    float o1 = dy * rs * g[c + 1] + be[c + 1];
    float o2 = dz * rs * g[c + 2] + be[c + 2];
    float o3 = dw * rs * g[c + 3] + be[c + 3];
    if (outf) {
        float4 o; o.x = o0; o.y = o1; o.z = o2; o.w = o3;
        *(float4*)(outf + (size_t)row * 1024 + c) = o;
    }
    if (outb) {
        u16 t[4] = {f2bf(o0), f2bf(o1), f2bf(o2), f2bf(o3)};
        *(uint2*)&outb[(size_t)row * 1024 + c] = *(const uint2*)t;
    }
}

// ---------------- NT bf16 MFMA GEMM: C[M,N] = A[M,K] * Bt[N,K]^T, tile 128x128, BK=64 ----------------
template <int MODE>
__global__ __launch_bounds__(256) void gemm_nt(
    const u16* __restrict__ A, const u16* __restrict__ Bt, int K, int N,
    const float* __restrict__ bias0, const float* __restrict__ bias1,
    const float* __restrict__ bias2, const float* __restrict__ aux,
    float* __restrict__ o0, float* __restrict__ o1, u16* __restrict__ ob,
    const int* __restrict__ kvidx) {
    __shared__ u16 As[128 * 64];
    __shared__ u16 Bs[128 * 64];
    int tid = threadIdx.x;
    int l = tid & 63, w = tid >> 6;
    int wr = w >> 1, wc = w & 1;
    int lr = l & 15, lg = l >> 4;
    int m0 = blockIdx.y * 128, n0 = blockIdx.x * 128;
    f32x4 acc[4][4] = {};
    for (int kb = 0; kb < K; kb += 64) {
#pragma unroll
        for (int pass = 0; pass < 4; ++pass) {
            int f = pass * 2048 + tid * 8;
            int r = f >> 6, c = f & 63;
            int sc = c ^ ((r & 7) << 3); // T2 XOR swizzle (16B granules)
            *(uint4*)&As[r * 64 + sc] = *(const uint4*)&A[(size_t)(m0 + r) * K + kb + c];
            *(uint4*)&Bs[r * 64 + sc] = *(const uint4*)&Bt[(size_t)(n0 + r) * K + kb + c];
        }
        __syncthreads();
#pragma unroll
        for (int kk = 0; kk < 2; ++kk) {
            short8 a[4], b[4];
            int c0 = kk * 32 + lg * 8;
#pragma unroll
            for (int mi = 0; mi < 4; mi++) {
                int row = wr * 64 + mi * 16 + lr;
                a[mi] = *(const short8*)&As[row * 64 + (c0 ^ ((row & 7) << 3))];
            }
#pragma unroll
            for (int ni = 0; ni < 4; ni++) {
                int row = wc * 64 + ni * 16 + lr;
                b[ni] = *(const short8*)&Bs[row * 64 + (c0 ^ ((row & 7) << 3))];
            }
#pragma unroll
            for (int mi = 0; mi < 4; mi++)
#pragma unroll
                for (int ni = 0; ni < 4; ni++)
                    acc[mi][ni] = __builtin_amdgcn_mfma_f32_16x16x32_bf16(
                        a[mi], b[ni], acc[mi][ni], 0, 0, 0);
        }
        __syncthreads();
    }
    // epilogue: C row = m0+wr*64+mi*16+lg*4+r ; col = n0+wc*64+ni*16+lr
#pragma unroll
    for (int mi = 0; mi < 4; mi++) {
#pragma unroll
        for (int ni = 0; ni < 4; ni++) {
#pragma unroll
            for (int r = 0; r < 4; r++) {
                int row = m0 + wr * 64 + mi * 16 + lg * 4 + r;
                int col = n0 + wc * 64 + ni * 16 + lr;
                float v = acc[mi][ni][r];
                if constexpr (MODE == MODE_QKV) {
                    int sel = col >> 10, c = col & 1023;
                    if (sel == 0) {
                        ob[(size_t)row * 1024 + c] = f2bf((v + bias0[c]) * 0.125f);
                    } else {
                        float val = v + (sel == 1 ? bias1[c] : bias2[c]);
                        int b = row >> 8, ii = row & 255;
                        int page = kvidx[b * 256 + 240 + (ii >> 4)];
                        o0[(size_t)page * 32768 + (sel == 2 ? 16384 : 0) + (ii & 15) * 1024 + c] = val;
                    }
                } else if constexpr (MODE == MODE_WO) {
                    o0[(size_t)row * N + col] = v + bias0[col] + aux[(size_t)row * N + col];
                } else if constexpr (MODE == MODE_F1) {
                    float t = v + bias0[col];
                    ob[(size_t)row * N + col] = f2bf(fmaxf(t, 0.0f));
                } else {
                    float t = v + bias0[col];
                    o0[(size_t)row * N + col] = t;
                    o1[(size_t)row * N + col] = t + aux[(size_t)row * N + col];
                }
            }
        }
    }
}

// ---------------- flash attention: grid (qt=4, h=16, b=8), 4 waves, QBLK=64, KVB=64 ----------------
__global__ __launch_bounds__(256) void attn_kernel(const u16* __restrict__ qb,
                                                   const float* __restrict__ ptO,
                                                   const int* __restrict__ kvidx,
                                                   u16* __restrict__ ctxb) {
    __shared__ u16 Ks[64 * 64];
    __shared__ u16 Vt[64 * 64];       // transposed: [d][t]
    __shared__ u16 Ps[4][16 * 64];    // per wave
    int tid = threadIdx.x;
    int l = tid & 63, w = tid >> 6;
    int lr = l & 15, lg = l >> 4;
    int qt = blockIdx.x, h = blockIdx.y, b = blockIdx.z;

    int qrow = qt * 64 + w * 16 + lr;
    const u16* qptr = qb + (size_t)(b * 256 + qrow) * 1024 + h * 64 + lg * 8;
    short8 qf0 = *(const short8*)qptr;
    short8 qf1 = *(const short8*)(qptr + 32);

    f32x4 octx[4] = {};
    float mrow[4], lrow[4];
#pragma unroll
    for (int r = 0; r < 4; r++) { mrow[r] = -3.0e38f; lrow[r] = 0.0f; }

    int kv_hi = 3840 + qt * 64 + 64; // multiple of 64
    int sr = tid >> 2, sc = (tid & 3) * 16;
    for (int kt = 0; kt < kv_hi; kt += 64) {
        // ---- stage K (row-major, swizzled) and V (transposed, swizzled) ----
        {
            int t = kt + sr;
            int page = kvidx[b * 256 + (t >> 4)];
            const float* kp = ptO + (size_t)page * 32768 + (size_t)(t & 15) * 1024 + h * 64 + sc;
            u16 tmp[16];
#pragma unroll
            for (int j = 0; j < 16; j += 4) {
                float4 f4 = *(const float4*)(kp + j);
                tmp[j] = f2bf(f4.x); tmp[j + 1] = f2bf(f4.y);
                tmp[j + 2] = f2bf(f4.z); tmp[j + 3] = f2bf(f4.w);
            }
            int s0 = sc ^ ((sr & 7) << 3), s1 = (sc + 8) ^ ((sr & 7) << 3);
            *(uint4*)&Ks[sr * 64 + s0] = *(const uint4*)&tmp[0];
            *(uint4*)&Ks[sr * 64 + s1] = *(const uint4*)&tmp[8];
            const float* vp = kp + 16384;
#pragma unroll
            for (int j = 0; j < 16; j += 4) {
                float4 f4 = *(const float4*)(vp + j);
                int d0 = sc + j;
                Vt[(d0 + 0) * 64 + (sr ^ (((d0 + 0) & 7) << 3))] = f2bf(f4.x);
                Vt[(d0 + 1) * 64 + (sr ^ (((d0 + 1) & 7) << 3))] = f2bf(f4.y);
                Vt[(d0 + 2) * 64 + (sr ^ (((d0 + 2) & 7) << 3))] = f2bf(f4.z);
                Vt[(d0 + 3) * 64 + (sr ^ (((d0 + 3) & 7) << 3))] = f2bf(f4.w);
            }
        }
        __syncthreads();
        // ---- scores: S[16q x 64kv] per wave ----
        float S[4][4];
#pragma unroll
        for (int ni = 0; ni < 4; ni++) {
            f32x4 s = {};
            int krow = ni * 16 + lr;
            int swz = (krow & 7) << 3;
            short8 k0 = *(const short8*)&Ks[krow * 64 + ((lg * 8) ^ swz)];
            short8 k1 = *(const short8*)&Ks[krow * 64 + ((32 + lg * 8) ^ swz)];
            s = __builtin_amdgcn_mfma_f32_16x16x32_bf16(qf0, k0, s, 0, 0, 0);
            s = __builtin_amdgcn_mfma_f32_16x16x32_bf16(qf1, k1, s, 0, 0, 0);
            int col = kt + ni * 16 + lr;
#pragma unroll
            for (int r = 0; r < 4; r++) {
                int q = qt * 64 + w * 16 + lg * 4 + r;
                S[ni][r] = (col <= 3840 + q) ? s[r] : -1.0e30f;
            }
        }
        // ---- online softmax ----
#pragma unroll
        for (int r = 0; r < 4; r++) {
            float m4 = fmaxf(fmaxf(S[0][r], S[1][r]), fmaxf(S[2][r], S[3][r]));
#pragma unroll
            for (int msk = 1; msk < 16; msk <<= 1) m4 = fmaxf(m4, __shfl_xor(m4, msk, 64));
            float mnew = fmaxf(mrow[r], m4);
            float scale = __expf(mrow[r] - mnew);
            mrow[r] = mnew;
            float ts = 0.0f;
#pragma unroll
            for (int ni = 0; ni < 4; ni++) {
                float p = __expf(S[ni][r] - mnew);
                S[ni][r] = p;
                ts += p;
            }
#pragma unroll
            for (int msk = 1; msk < 16; msk <<= 1) ts += __shfl_xor(ts, msk, 64);
            lrow[r] = lrow[r] * scale + ts;
#pragma unroll
            for (int dt = 0; dt < 4; dt++) octx[dt][r] *= scale;
        }
        // ---- write P to per-wave LDS (swizzled) ----
#pragma unroll
        for (int ni = 0; ni < 4; ni++)
#pragma unroll
            for (int r = 0; r < 4; r++) {
                int prow = lg * 4 + r;
                Ps[w][prow * 64 + ((ni * 16 + lr) ^ ((prow & 7) << 3))] = f2bf(S[ni][r]);
            }
        // ---- PV ----
#pragma unroll
        for (int kk = 0; kk < 2; kk++) {
            int c0 = kk * 32 + lg * 8;
            short8 pf = *(const short8*)&Ps[w][lr * 64 + (c0 ^ ((lr & 7) << 3))];
#pragma unroll
            for (int dt = 0; dt < 4; dt++) {
                int vrow = dt * 16 + lr;
                short8 vf = *(const short8*)&Vt[vrow * 64 + (c0 ^ ((vrow & 7) << 3))];
                octx[dt] = __builtin_amdgcn_mfma_f32_16x16x32_bf16(pf, vf, octx[dt], 0, 0, 0);
            }
        }
        __syncthreads();
    }
    // ---- output ----
#pragma unroll
    for (int dt = 0; dt < 4; dt++)
#pragma unroll
        for (int r = 0; r < 4; r++) {
            float o = octx[dt][r] / lrow[r];
            int row = b * 256 + qt * 64 + w * 16 + lg * 4 + r;
            int col = h * 64 + dt * 16 + lr;
            ctxb[(size_t)row * 1024 + col] = f2bf(o);
        }
}

// ---------------- launch ----------------
extern "C" void kernel_launch(void* const* d_in, const int* in_sizes, int n_in,
                              void* d_out, int out_size, void* d_ws, size_t ws_size,
                              hipStream_t stream) {
    (void)in_sizes; (void)n_in; (void)out_size; (void)ws_size;
    const float* x   = (const float*)d_in[0];
    const float* pgt = (const float*)d_in[1];
    const float* Wq  = (const float*)d_in[2];
    const float* bq  = (const float*)d_in[3];
    const float* Wk  = (const float*)d_in[4];
    const float* bk  = (const float*)d_in[5];
    const float* Wv  = (const float*)d_in[6];
    const float* bv  = (const float*)d_in[7];
    const float* Wo  = (const float*)d_in[8];
    const float* bo  = (const float*)d_in[9];
    const float* ln1g = (const float*)d_in[10];
    const float* ln1b = (const float*)d_in[11];
    const float* W1  = (const float*)d_in[12];
    const float* b1  = (const float*)d_in[13];
    const float* W2  = (const float*)d_in[14];
    const float* b2  = (const float*)d_in[15];
    const float* lnfg = (const float*)d_in[16];
    const float* lnfb = (const float*)d_in[17];
    const int* kvidx = (const int*)d_in[20];

    float* out = (float*)d_out;
    float* out_x  = out;
    float* out_lr = out + 2048 * 1024;
    float* out_pt = out + 2 * 2048 * 1024;

    char* ws = (char*)d_ws;
    size_t off = 0;
    auto alloc = [&](size_t bytes) { void* p = ws + off; off += (bytes + 255) & ~(size_t)255; return p; };
    u16* WqkvT = (u16*)alloc((size_t)3072 * 1024 * 2);
    u16* WoT   = (u16*)alloc((size_t)1024 * 1024 * 2);
    u16* W1T   = (u16*)alloc((size_t)4096 * 1024 * 2);
    u16* W2T   = (u16*)alloc((size_t)1024 * 4096 * 2);
    u16* xb    = (u16*)alloc((size_t)2048 * 1024 * 2);
    u16* qbuf  = (u16*)alloc((size_t)2048 * 1024 * 2);
    u16* ctxb  = (u16*)alloc((size_t)2048 * 1024 * 2);
    u16* xln1b = (u16*)alloc((size_t)2048 * 1024 * 2);
    u16* hb    = (u16*)alloc((size_t)2048 * 4096 * 2);
    float* t1    = (float*)alloc((size_t)2048 * 1024 * 4);
    float* xln1f = (float*)alloc((size_t)2048 * 1024 * 4);
    float* t2 = t1; // t1 dead after LN1

    dim3 tb(32, 8);
    transpose_cast<<<dim3(32, 32), tb, 0, stream>>>(Wq, WqkvT, 1024, 1024);
    transpose_cast<<<dim3(32, 32), tb, 0, stream>>>(Wk, WqkvT + 1024 * 1024, 1024, 1024);
    transpose_cast<<<dim3(32, 32), tb, 0, stream>>>(Wv, WqkvT + 2048 * 1024, 1024, 1024);
    transpose_cast<<<dim3(32, 32), tb, 0, stream>>>(Wo, WoT, 1024, 1024);
    transpose_cast<<<dim3(128, 32), tb, 0, stream>>>(W1, W1T, 1024, 4096);
    transpose_cast<<<dim3(32, 128), tb, 0, stream>>>(W2, W2T, 4096, 1024);
    cast_f2b<<<1024, 256, 0, stream>>>(x, xb, 2048 * 1024 / 8);
    copy_f4<<<4096, 256, 0, stream>>>((const float4*)pgt, (float4*)out_pt, 67108864 / 4);
    // QKV: writes q (scaled, bf16) and scatters k/v into out_pt new pages
    gemm_nt<MODE_QKV><<<dim3(24, 16), 256, 0, stream>>>(xb, WqkvT, 1024, 3072,
        bq, bk, bv, nullptr, out_pt, nullptr, qbuf, kvidx);
    attn_kernel<<<dim3(4, 16, 8), 256, 0, stream>>>(qbuf, out_pt, kvidx, ctxb);
    gemm_nt<MODE_WO><<<dim3(8, 16), 256, 0, stream>>>(ctxb, WoT, 1024, 1024,
        bo, nullptr, nullptr, x, t1, nullptr, nullptr, nullptr);
    ln_row<<<2048, 256, 0, stream>>>(t1, ln1g, ln1b, xln1f, xln1b);
    gemm_nt<MODE_F1><<<dim3(32, 16), 256, 0, stream>>>(xln1b, W1T, 1024, 4096,
        b1, nullptr, nullptr, nullptr, nullptr, nullptr, hb, nullptr);
    gemm_nt<MODE_F2><<<dim3(8, 16), 256, 0, stream>>>(hb, W2T, 4096, 1024,
        b2, nullptr, nullptr, xln1f, out_lr, t2, nullptr, nullptr);
    ln_row<<<2048, 256, 0, stream>>>(t2, lnfg, lnfb, out_x, nullptr);
}